// Round 5
// baseline (742.232 us; speedup 1.0000x reference)
//
#include <hip/hip_runtime.h>

#define N_NODES 10242
#define NNZ_E   71694
// rows padded to multiple of 8
#define NNZ_PAD_MAX (NNZ_E + 7 * N_NODES + 64)
#define BT      32      // B*T
#define C_IN    16
#define K_S     20
#define C_OUT   32
#define F       512     // BT * C_IN
typedef unsigned short u16;
typedef unsigned int   u32;

#define RING_ELEMS ((size_t)N_NODES * F)    // f16 elems per ring slot, layout [n][bt*16+c]
#define RING_BYTES (RING_ELEMS * 2)         // ~10.5 MB

#define NSLICE  8
#define SLICE_U16 (F / NSLICE)

typedef __attribute__((ext_vector_type(8)))  _Float16 half8;
typedef __attribute__((ext_vector_type(16))) float    float16;

__device__ __forceinline__ void unpack8h(uint4 u, float* f) {
    union { uint4 u; _Float16 h[8]; } v; v.u = u;
    #pragma unroll
    for (int i = 0; i < 8; ++i) f[i] = (float)v.h[i];
}
__device__ __forceinline__ uint4 pack8h(const float* f) {
    union { uint4 u; _Float16 h[8]; } v;
    #pragma unroll
    for (int i = 0; i < 8; ++i) v.h[i] = (_Float16)f[i];
    return v.u;
}
__device__ __forceinline__ u16 f2h(float f) {
    union { _Float16 h; u16 u; } v; v.h = (_Float16)f; return v.u;
}
__device__ __forceinline__ float h2f_lo(u32 w) {
    union { u32 u; _Float16 h[2]; } v; v.u = w; return (float)v.h[0];
}
__device__ __forceinline__ float h2f_hi(u32 w) {
    union { u32 u; _Float16 h[2]; } v; v.u = w; return (float)v.h[1];
}
__device__ __forceinline__ u32 packh2(float a, float b) {
    union { u32 u; _Float16 h[2]; } v; v.h[0] = (_Float16)a; v.h[1] = (_Float16)b; return v.u;
}

// ---------------- parallel CSR build -----------------
// Determinism: per-row (col,valbits) multiset is fixed; in-row sort makes the
// CSR — and hence f32 accumulation order — deterministic. Rows padded to x8
// with (col=0, val=0) entries (contribute exactly 0).

__global__ __launch_bounds__(256) void init_kernel(
        const float* __restrict__ W, int* __restrict__ cnt,
        u16* __restrict__ wtfrag) {
    int i = blockIdx.x * 256 + threadIdx.x;
    if (i < N_NODES) cnt[i] = 0;
    int w = i - N_NODES;
    if (w >= 0 && w < K_S * 64 * 8) {
        // B-frag for v_mfma_f32_32x32x16_f16: lane L, reg j ->
        // B[k=8*(L>>5)+j][col=L&31] = W[cout=col][c=k][k_cheb]
        int j    = w & 7;
        int lane = (w >> 3) & 63;
        int k    = w >> 9;
        int cout = lane & 31;
        int c    = ((lane >> 5) << 3) + j;
        wtfrag[w] = f2h(W[cout * (C_IN * K_S) + c * K_S + k]);
    }
}

__global__ __launch_bounds__(256) void count_kernel(
        const int* __restrict__ erow, int* cnt) {
    int e = blockIdx.x * 256 + threadIdx.x;
    if (e < NNZ_E) atomicAdd(&cnt[erow[e]], 1);
}

// exclusive scan of x8-padded counts + len-class histogram bases
__global__ __launch_bounds__(256) void scan_kernel(
        const int* __restrict__ cnt, int* row_ptr, int* cursor,
        int* class_cursor) {
    const int T = 256;
    const int chunk = (N_NODES + T - 1) / T;  // 41
    __shared__ int part[T];
    __shared__ int ccnt[8];
    int t = threadIdx.x;
    if (t < 8) ccnt[t] = 0;
    __syncthreads();
    int base = t * chunk;
    int s = 0;
    for (int i = 0; i < chunk; ++i) {
        int idx = base + i;
        if (idx < N_NODES) {
            int pl = (cnt[idx] + 7) & ~7;
            s += pl;
            int cls = (pl == 0) ? 0 : ((pl >> 3) - 1);
            if (cls > 7) cls = 7;
            atomicAdd(&ccnt[cls], 1);
        }
    }
    part[t] = s;
    __syncthreads();
    for (int off = 1; off < T; off <<= 1) {
        int v = (t >= off) ? part[t - off] : 0;
        __syncthreads();
        part[t] += v;
        __syncthreads();
    }
    int run = (t == 0) ? 0 : part[t - 1];
    for (int i = 0; i < chunk; ++i) {
        int idx = base + i;
        if (idx < N_NODES) {
            row_ptr[idx] = run;
            cursor[idx]  = run;
            run += (cnt[idx] + 7) & ~7;
        }
    }
    if (t == T - 1) row_ptr[N_NODES] = part[T - 1];
    __syncthreads();
    if (t == 0) {
        int r2 = 0;
        for (int c2 = 0; c2 < 8; ++c2) { class_cursor[c2] = r2; r2 += ccnt[c2]; }
    }
}

__global__ __launch_bounds__(256) void scatter_kernel(
        const int* __restrict__ erow, const int* __restrict__ ecol,
        const float* __restrict__ eval, int* cursor, int2* __restrict__ cpack) {
    int e = blockIdx.x * 256 + threadIdx.x;
    if (e < NNZ_E) {
        int p = atomicAdd(&cursor[erow[e]], 1);
        cpack[p] = make_int2(ecol[e], __float_as_int(eval[e]));
    }
}

// per-row sort + pad fill + compact 4B edge pack (col u16 | val f16)
__global__ __launch_bounds__(256) void finalize_kernel(
        const int* __restrict__ row_ptr, const int* __restrict__ cursor,
        int2* cpack, u32* __restrict__ epack) {
    int r = blockIdx.x * 256 + threadIdx.x;
    if (r >= N_NODES) return;
    int sbeg = row_ptr[r];
    int send = cursor[r];        // sbeg + real count
    int pend = row_ptr[r + 1];   // sbeg + padded count
    for (int i = sbeg + 1; i < send; ++i) {
        int2 key = cpack[i];
        int j = i - 1;
        while (j >= sbeg) {
            int2 q = cpack[j];
            bool gt = (q.x > key.x) || (q.x == key.x && (u32)q.y > (u32)key.y);
            if (!gt) break;
            cpack[j + 1] = q;
            --j;
        }
        cpack[j + 1] = key;
    }
    for (int p = send; p < pend; ++p) cpack[p] = make_int2(0, 0);
    for (int p = sbeg; p < pend; ++p) {
        int2 q = cpack[p];
        epack[p] = ((u32)q.x & 0xFFFFu) |
                   ((u32)f2h(__int_as_float(q.y)) << 16);
    }
}

// bucket nodes by padded len so chain waves don't pay masked tail iterations
__global__ __launch_bounds__(256) void order_kernel(
        const int* __restrict__ row_ptr, int* class_cursor,
        int* __restrict__ node_order) {
    int n = blockIdx.x * 256 + threadIdx.x;
    if (n >= N_NODES) return;
    int pl = row_ptr[n + 1] - row_ptr[n];
    int cls = (pl == 0) ? 0 : ((pl >> 3) - 1);
    if (cls > 7) cls = 7;
    int pos = atomicAdd(&class_cursor[cls], 1);
    node_order[pos] = n;
}

// ---------------- fused Chebyshev chain: one kernel, zero grid syncs -------
// The recurrence couples rows, never columns: WG b owns column pair
// f0 = (b&7)*64 + (b>>3)*2 (XCD-aligned so same-XCD L2 merges ring-write
// sectors), keeps T_{k-1}/T_{k-2} for ALL nodes in LDS (2x10242x4B = 80KB),
// iterates all 19 steps with __syncthreads() only. Streams each T_k slice
// to the global ring for the MFMA projection.

__global__ __launch_bounds__(1024) void chain_kernel(
        const float* __restrict__ x, const int* __restrict__ row_ptr,
        const u32* __restrict__ epack, const int* __restrict__ node_order,
        u16* __restrict__ ring) {
    __shared__ u32 Tsh[2][N_NODES];
    const int t  = threadIdx.x;
    const int b  = blockIdx.x;
    const int f0 = ((b & 7) << 6) | ((b >> 3) << 1);
    const int bt = f0 >> 4;
    const int c0 = f0 & 15;

    // k = 0: transform x -> T0 (LDS + ring slot 0)
    for (int i = t; i < N_NODES; i += 1024) {
        const float* xp = x + ((size_t)bt * N_NODES + i) * C_IN + c0;
        float2 xv = *(const float2*)xp;
        u32 p = packh2(xv.x, xv.y);
        Tsh[0][i] = p;
        *(u32*)(ring + (size_t)i * F + f0) = p;
    }
    __syncthreads();

    int cur = 0;
    for (int k = 1; k < K_S; ++k) {
        const u32* bsrc = &Tsh[cur][0];
        u32* adst = &Tsh[cur ^ 1][0];
        u16* rk = ring + (size_t)k * RING_ELEMS;
        const float alpha = (k == 1) ? 1.f : 2.f;
        const bool hasA = (k >= 2);
        for (int i = t; i < N_NODES; i += 1024) {
            int n = node_order[i];
            int s = row_ptr[n], e = row_ptr[n + 1];
            float a0 = 0.f, a1 = 0.f;
            if (hasA) { u32 ap = adst[n]; a0 = h2f_lo(ap); a1 = h2f_hi(ap); }
            float acc0 = 0.f, acc1 = 0.f;
            for (int p = s; p < e; p += 8) {
                uint4 q0 = *(const uint4*)(epack + p);
                uint4 q1 = *(const uint4*)(epack + p + 4);
                #define EDGE(u) { u32 cc = (u) & 0xFFFFu; u32 d = bsrc[cc]; \
                    float vv = h2f_hi(u); \
                    acc0 += vv * h2f_lo(d); acc1 += vv * h2f_hi(d); }
                EDGE(q0.x) EDGE(q0.y) EDGE(q0.z) EDGE(q0.w)
                EDGE(q1.x) EDGE(q1.y) EDGE(q1.z) EDGE(q1.w)
                #undef EDGE
            }
            float y0 = alpha * acc0 - (hasA ? a0 : 0.f);
            float y1 = alpha * acc1 - (hasA ? a1 : 0.f);
            u32 yp = packh2(y0, y1);
            adst[n] = yp;                                  // in-place: T_k over T_{k-2}
            *(u32*)(rk + (size_t)n * F + f0) = yp;
        }
        __syncthreads();
        cur ^= 1;
    }
}

// ---------------- MFMA projection over all K_S slots, f16 ------------------
// per wave: one node; tile M=32(bt) x N=32(cout), K=kcnt*16.
// A: m=L&31, kk=8*(L>>5)+j ; C/D: col=L&31, row=(reg&3)+8*(reg>>2)+4*(L>>5)

__global__ __launch_bounds__(256) void proj_mfma_kernel(
        const u16* __restrict__ ring, int R, int k0, int kcnt,
        const u16* __restrict__ wtfrag, float* __restrict__ out, int accumulate) {
    const int lane = threadIdx.x & 63;
    const int n = (blockIdx.x << 2) + (threadIdx.x >> 6);
    if (n >= N_NODES) return;
    const int col = lane & 31;
    const int grp = lane >> 5;
    const size_t aoff = (size_t)n * F + (size_t)col * 16 + grp * 8;

    union U { uint4 u; half8 h; };
    float16 acc0 = {};
    float16 acc1 = {};
    int j = 0;
    for (; j + 2 <= kcnt; j += 2) {
        int ka = k0 + j, kb = k0 + j + 1;
        U a0, b0, a1, b1;
        a0.u = *(const uint4*)(ring + (size_t)(ka % R) * RING_ELEMS + aoff);
        b0.u = *(const uint4*)(wtfrag + (size_t)ka * 512 + lane * 8);
        a1.u = *(const uint4*)(ring + (size_t)(kb % R) * RING_ELEMS + aoff);
        b1.u = *(const uint4*)(wtfrag + (size_t)kb * 512 + lane * 8);
        acc0 = __builtin_amdgcn_mfma_f32_32x32x16_f16(a0.h, b0.h, acc0, 0, 0, 0);
        acc1 = __builtin_amdgcn_mfma_f32_32x32x16_f16(a1.h, b1.h, acc1, 0, 0, 0);
    }
    if (j < kcnt) {
        int ka = k0 + j;
        U a0, b0;
        a0.u = *(const uint4*)(ring + (size_t)(ka % R) * RING_ELEMS + aoff);
        b0.u = *(const uint4*)(wtfrag + (size_t)ka * 512 + lane * 8);
        acc0 = __builtin_amdgcn_mfma_f32_32x32x16_f16(a0.h, b0.h, acc0, 0, 0, 0);
    }

    #pragma unroll
    for (int r = 0; r < 16; ++r) {
        int bt = (r & 3) + 8 * (r >> 2) + 4 * grp;
        float* op = out + ((size_t)bt * N_NODES + n) * C_OUT + col;
        float val = acc0[r] + acc1[r];
        if (accumulate) *op += val;
        else            *op  = val;
    }
}

// ---------------- fallback path kernels (used only if workspace < 20 slots) -

__global__ __launch_bounds__(256) void transform_kernel(
        const float* __restrict__ x, u16* __restrict__ T0) {
    int g = blockIdx.x * 256 + threadIdx.x;
    int n   = g >> 9;
    int rem = g & 511;
    int bt  = rem >> 4;
    int c   = rem & 15;
    float v = x[((size_t)bt * N_NODES + n) * C_IN + c];
    T0[(size_t)n * F + rem] = f2h(v);
}

__global__ __launch_bounds__(256) void spmm_slice_kernel(
        const u16* __restrict__ srcB, const u16* __restrict__ srcA,
        u16* __restrict__ dst,
        const int* __restrict__ row_ptr, const int2* __restrict__ cpack,
        float alpha, float beta) {
    const int slice = blockIdx.x & 7;
    const int chunk = blockIdx.x >> 3;
    const int wave  = threadIdx.x >> 6;
    const int lane  = threadIdx.x & 63;
    const int l     = lane & 7;
    const int n     = chunk * 32 + wave * 8 + (lane >> 3);
    const bool valid = (n < N_NODES);

    const int s   = valid ? row_ptr[n] : 0;
    const int len = valid ? (row_ptr[n + 1] - s) : 0;
    const size_t soff = (size_t)slice * SLICE_U16 + (size_t)l * 8;

    float a[8] = {0,0,0,0,0,0,0,0};
    if (beta != 0.f && valid) {
        uint4 ua = *(const uint4*)(srcA + (size_t)n * F + soff);
        unpack8h(ua, a);
    }
    float acc[8] = {0,0,0,0,0,0,0,0};
    const int gbase = lane & 56;
    for (int c = 0; c * 8 < len; ++c) {
        int2 my = cpack[s + c * 8 + l];
        int col[8]; float v[8];
        #pragma unroll
        for (int r = 0; r < 8; ++r) {
            col[r] = __shfl(my.x, gbase + r, 64);
            v[r]   = __int_as_float(__shfl(my.y, gbase + r, 64));
        }
        #pragma unroll
        for (int r = 0; r < 8; ++r) {
            uint4 g = *(const uint4*)(srcB + (size_t)col[r] * F + soff);
            float bb[8];
            unpack8h(g, bb);
            #pragma unroll
            for (int i = 0; i < 8; ++i) acc[i] += v[r] * bb[i];
        }
    }
    if (valid) {
        float y[8];
        #pragma unroll
        for (int i = 0; i < 8; ++i) y[i] = alpha * acc[i] + beta * a[i];
        *(uint4*)(dst + (size_t)n * F + soff) = pack8h(y);
    }
}

// ---------------- host launch ----------------

extern "C" void kernel_launch(void* const* d_in, const int* in_sizes, int n_in,
                              void* d_out, int out_size, void* d_ws, size_t ws_size,
                              hipStream_t stream) {
    const float* x    = (const float*)d_in[0];
    const int*   erow = (const int*)  d_in[1];
    const int*   ecol = (const int*)  d_in[2];
    const float* eval = (const float*)d_in[3];
    const float* W    = (const float*)d_in[4];
    float* out = (float*)d_out;

    char* ws = (char*)d_ws;
    size_t o = 0;
    auto alloc = [&](size_t bytes) -> char* {
        o = (o + 511) & ~(size_t)511;
        char* r = ws + o;
        o += bytes;
        return r;
    };
    int*   cnt      = (int*)  alloc((size_t)N_NODES * 4);
    int*   row_ptr  = (int*)  alloc((size_t)(N_NODES + 1) * 4);
    int*   cursor   = (int*)  alloc((size_t)N_NODES * 4);
    int2*  cpack    = (int2*) alloc((size_t)NNZ_PAD_MAX * 8);
    u32*   epack    = (u32*)  alloc((size_t)NNZ_PAD_MAX * 4);
    u16*   wtfrag   = (u16*)  alloc((size_t)K_S * 512 * 2);
    int*   clscur   = (int*)  alloc(8 * 4);
    int*   norder   = (int*)  alloc((size_t)N_NODES * 4);

    o = (o + 511) & ~(size_t)511;
    int R = (int)((ws_size - o) / RING_BYTES);
    if (R > K_S) R = K_S;
    if (R < 3)  R = 3;
    u16* ring = (u16*)(ws + o);
    auto slot = [&](int k) -> u16* { return ring + (size_t)(k % R) * RING_ELEMS; };

    // CSR build: 6 small parallel kernels
    init_kernel<<<(N_NODES + K_S * 512 + 255) / 256, 256, 0, stream>>>(W, cnt, wtfrag);
    count_kernel<<<(NNZ_E + 255) / 256, 256, 0, stream>>>(erow, cnt);
    scan_kernel<<<1, 256, 0, stream>>>(cnt, row_ptr, cursor, clscur);
    scatter_kernel<<<(NNZ_E + 255) / 256, 256, 0, stream>>>(erow, ecol, eval, cursor, cpack);
    finalize_kernel<<<(N_NODES + 255) / 256, 256, 0, stream>>>(row_ptr, cursor, cpack, epack);
    order_kernel<<<(N_NODES + 255) / 256, 256, 0, stream>>>(row_ptr, clscur, norder);

    const int grid4 = (N_NODES + 3) / 4;

    if (R >= K_S) {
        // fused chain: transform + 19 Chebyshev steps, one dispatch
        chain_kernel<<<256, 1024, 0, stream>>>(x, row_ptr, epack, norder, ring);
        // single MFMA projection pass over all 20 slots
        proj_mfma_kernel<<<grid4, 256, 0, stream>>>(
            ring, K_S, 0, K_S, wtfrag, out, 0);
        return;
    }

    // fallback: multi-launch pipeline (round-4 structure)
    const int gridsl = NSLICE * ((N_NODES + 31) / 32);
    int c0 = 0;
    auto maybe_pass = [&](int k_done) {
        int target = K_S - c0;
        if (target > R) target = R;
        if (target > 0 && (k_done - c0 + 1) == target) {
            proj_mfma_kernel<<<grid4, 256, 0, stream>>>(
                ring, R, c0, target, wtfrag, out, (c0 > 0) ? 1 : 0);
            c0 += target;
        }
    };
    transform_kernel<<<(int)(RING_ELEMS / 256), 256, 0, stream>>>(x, slot(0));
    maybe_pass(0);
    for (int k = 1; k < K_S; ++k) {
        const u16* srcB = slot(k - 1);
        const u16* srcA = (k >= 2) ? slot(k - 2) : slot(k - 1);
        float alpha = (k == 1) ? 1.f : 2.f;
        float beta  = (k == 1) ? 0.f : -1.f;
        spmm_slice_kernel<<<gridsl, 256, 0, stream>>>(
            srcB, srcA, slot(k), row_ptr, cpack, alpha, beta);
        maybe_pass(k);
    }
}

// Round 6
// 472.552 us; speedup vs baseline: 1.5707x; 1.5707x over previous
//
#include <hip/hip_runtime.h>

#define N_NODES 10242
#define NNZ_E   71694
// rows padded to multiple of 8, +64 slack for the cooperative row over-read
#define NNZ_PAD_MAX (NNZ_E + 7 * N_NODES + 64)
#define BT      32      // B*T
#define C_IN    16
#define K_S     20
#define C_OUT   32
#define F       512     // BT * C_IN
typedef unsigned short u16;
typedef unsigned int   u32;

#define RING_ELEMS ((size_t)N_NODES * F)    // f16 elems per ring slot, layout [n][bt*16+c]
#define RING_BYTES (RING_ELEMS * 2)         // ~10.5 MB

typedef __attribute__((ext_vector_type(8)))  _Float16 half8;
typedef __attribute__((ext_vector_type(16))) float    float16;

__device__ __forceinline__ void unpack8h(uint4 u, float* f) {
    union { uint4 u; _Float16 h[8]; } v; v.u = u;
    #pragma unroll
    for (int i = 0; i < 8; ++i) f[i] = (float)v.h[i];
}
__device__ __forceinline__ uint4 pack8h(const float* f) {
    union { uint4 u; _Float16 h[8]; } v;
    #pragma unroll
    for (int i = 0; i < 8; ++i) v.h[i] = (_Float16)f[i];
    return v.u;
}
__device__ __forceinline__ u16 f2h(float f) {
    union { _Float16 h; u16 u; } v; v.h = (_Float16)f; return v.u;
}

// ---------------- parallel CSR build (5 small wide-grid kernels) -----------
// Determinism: scatter order is nondeterministic, but each row's (col,valbits)
// multiset is fixed; in-row sort by (col, valbits) makes the final CSR — and
// hence the f32 accumulation order — fully deterministic. Rows padded to x8
// with (col=0, val=0) entries (contribute exactly 0).

__global__ __launch_bounds__(256) void init_kernel(
        const float* __restrict__ W, int* __restrict__ cnt,
        u16* __restrict__ wtfrag) {
    int i = blockIdx.x * 256 + threadIdx.x;
    if (i < N_NODES) cnt[i] = 0;
    int w = i - N_NODES;
    if (w >= 0 && w < K_S * 64 * 8) {
        // B-frag for v_mfma_f32_32x32x16_f16: lane L, reg j ->
        // B[k=8*(L>>5)+j][col=L&31] = W[cout=col][c=k][k_cheb]
        int j    = w & 7;
        int lane = (w >> 3) & 63;
        int k    = w >> 9;
        int cout = lane & 31;
        int c    = ((lane >> 5) << 3) + j;
        wtfrag[w] = f2h(W[cout * (C_IN * K_S) + c * K_S + k]);
    }
}

__global__ __launch_bounds__(256) void count_kernel(
        const int* __restrict__ erow, int* cnt) {
    int e = blockIdx.x * 256 + threadIdx.x;
    if (e < NNZ_E) atomicAdd(&cnt[erow[e]], 1);
}

__global__ __launch_bounds__(256) void scan_kernel(
        const int* __restrict__ cnt, int* row_ptr, int* cursor) {
    const int T = 256;
    const int chunk = (N_NODES + T - 1) / T;  // 41
    __shared__ int part[T];
    int t = threadIdx.x;
    int base = t * chunk;
    int s = 0;
    for (int i = 0; i < chunk; ++i) {
        int idx = base + i;
        if (idx < N_NODES) s += (cnt[idx] + 7) & ~7;
    }
    part[t] = s;
    __syncthreads();
    for (int off = 1; off < T; off <<= 1) {
        int v = (t >= off) ? part[t - off] : 0;
        __syncthreads();
        part[t] += v;
        __syncthreads();
    }
    int run = (t == 0) ? 0 : part[t - 1];
    for (int i = 0; i < chunk; ++i) {
        int idx = base + i;
        if (idx < N_NODES) {
            row_ptr[idx] = run;
            cursor[idx]  = run;
            run += (cnt[idx] + 7) & ~7;
        }
    }
    if (t == T - 1) row_ptr[N_NODES] = part[T - 1];
}

__global__ __launch_bounds__(256) void scatter_kernel(
        const int* __restrict__ erow, const int* __restrict__ ecol,
        const float* __restrict__ eval, int* cursor, int2* __restrict__ cpack) {
    int e = blockIdx.x * 256 + threadIdx.x;
    if (e < NNZ_E) {
        int p = atomicAdd(&cursor[erow[e]], 1);
        cpack[p] = make_int2(ecol[e], __float_as_int(eval[e]));
    }
}

__global__ __launch_bounds__(256) void finalize_kernel(
        const int* __restrict__ row_ptr, const int* __restrict__ cursor,
        int2* cpack) {
    int r = blockIdx.x * 256 + threadIdx.x;
    if (r >= N_NODES) return;
    int sbeg = row_ptr[r];
    int send = cursor[r];        // sbeg + real count
    int pend = row_ptr[r + 1];   // sbeg + padded count
    for (int i = sbeg + 1; i < send; ++i) {
        int2 key = cpack[i];
        int j = i - 1;
        while (j >= sbeg) {
            int2 q = cpack[j];
            bool gt = (q.x > key.x) || (q.x == key.x && (u32)q.y > (u32)key.y);
            if (!gt) break;
            cpack[j + 1] = q;
            --j;
        }
        cpack[j + 1] = key;
    }
    for (int p = send; p < pend; ++p) cpack[p] = make_int2(0, 0);
}

// ---------------- k=0,1 fused: transform + first SpMM ----------------------
// Wave per node. Computes T0[n] from fp32 x (writes slot0) AND
// T1[n] = L @ T0 gathered DIRECTLY from fp32 x (writes slot1).
// Replaces the separate transform dispatch; T1 sourced at full precision.
// Row layout per wave: lane covers bt=lane>>1, c=(lane&1)*8 .. +8.

__global__ __launch_bounds__(256) void spmm_first_kernel(
        const float* __restrict__ x,
        const int* __restrict__ row_ptr, const int2* __restrict__ cpack,
        u16* __restrict__ dst0, u16* __restrict__ dst1) {
    const int lane = threadIdx.x & 63;
    const int n = (blockIdx.x << 2) + (threadIdx.x >> 6);
    if (n >= N_NODES) return;
    const int s = row_ptr[n], e_end = row_ptr[n + 1];   // padded, multiple of 8

    const int bt = lane >> 1;
    const int hc = (lane & 1) * 8;
    const size_t xstride = (size_t)C_IN;   // per node within a bt panel

    // own T0 row
    const float* xo = x + ((size_t)bt * N_NODES + n) * xstride + hc;
    float4 o0 = *(const float4*)xo;
    float4 o1 = *(const float4*)(xo + 4);
    float t0[8] = {o0.x, o0.y, o0.z, o0.w, o1.x, o1.y, o1.z, o1.w};
    ((uint4*)(dst0 + (size_t)n * F))[lane] = pack8h(t0);

    int2 my = cpack[s + lane];   // padded row length <= ~24 << 64; +64 alloc slack

    float acc[8] = {0,0,0,0,0,0,0,0};
    for (int e = s; e < e_end; e += 8) {
        const int base = e - s;
        int   c[8]; float v[8];
        #pragma unroll
        for (int r = 0; r < 8; ++r) {
            c[r] = __builtin_amdgcn_readlane(my.x, base + r);
            v[r] = __int_as_float(__builtin_amdgcn_readlane(my.y, base + r));
        }
        #pragma unroll
        for (int r = 0; r < 8; ++r) {
            const float* xp = x + ((size_t)bt * N_NODES + c[r]) * xstride + hc;
            float4 f0 = *(const float4*)xp;
            float4 f1 = *(const float4*)(xp + 4);
            acc[0] += v[r] * f0.x; acc[1] += v[r] * f0.y;
            acc[2] += v[r] * f0.z; acc[3] += v[r] * f0.w;
            acc[4] += v[r] * f1.x; acc[5] += v[r] * f1.y;
            acc[6] += v[r] * f1.z; acc[7] += v[r] * f1.w;
        }
    }
    ((uint4*)(dst1 + (size_t)n * F))[lane] = pack8h(acc);
}

// ---------------- Chebyshev step: wave-per-node, f16 ring, fp32 math -------
// dst = alpha * L @ srcB + beta * srcA. Lane i holds cpack[s+i]; readlane
// broadcasts (col,val) so each 8-edge group issues ONE burst of 8 gathers.

__global__ __launch_bounds__(256) void spmm_step_kernel(
        const u16* __restrict__ srcB, const u16* __restrict__ srcA,
        u16* __restrict__ dst,
        const int* __restrict__ row_ptr, const int2* __restrict__ cpack,
        float alpha, float beta) {
    const int lane = threadIdx.x & 63;
    const int n = (blockIdx.x << 2) + (threadIdx.x >> 6);
    if (n >= N_NODES) return;
    const int s = row_ptr[n], e_end = row_ptr[n + 1];   // padded, multiple of 8

    // hoist srcA load (independent; overlaps the row fetch)
    float a[8] = {0,0,0,0,0,0,0,0};
    if (beta != 0.f) {
        uint4 ua = ((const uint4*)(srcA + (size_t)n * F))[lane];
        unpack8h(ua, a);
    }

    int2 my = cpack[s + lane];

    float acc0[8] = {0,0,0,0,0,0,0,0};
    float acc1[8] = {0,0,0,0,0,0,0,0};

    for (int e = s; e < e_end; e += 8) {
        const int base = e - s;
        int c0 = __builtin_amdgcn_readlane(my.x, base + 0);
        int c1 = __builtin_amdgcn_readlane(my.x, base + 1);
        int c2 = __builtin_amdgcn_readlane(my.x, base + 2);
        int c3 = __builtin_amdgcn_readlane(my.x, base + 3);
        int c4 = __builtin_amdgcn_readlane(my.x, base + 4);
        int c5 = __builtin_amdgcn_readlane(my.x, base + 5);
        int c6 = __builtin_amdgcn_readlane(my.x, base + 6);
        int c7 = __builtin_amdgcn_readlane(my.x, base + 7);
        float v0 = __int_as_float(__builtin_amdgcn_readlane(my.y, base + 0));
        float v1 = __int_as_float(__builtin_amdgcn_readlane(my.y, base + 1));
        float v2 = __int_as_float(__builtin_amdgcn_readlane(my.y, base + 2));
        float v3 = __int_as_float(__builtin_amdgcn_readlane(my.y, base + 3));
        float v4 = __int_as_float(__builtin_amdgcn_readlane(my.y, base + 4));
        float v5 = __int_as_float(__builtin_amdgcn_readlane(my.y, base + 5));
        float v6 = __int_as_float(__builtin_amdgcn_readlane(my.y, base + 6));
        float v7 = __int_as_float(__builtin_amdgcn_readlane(my.y, base + 7));

        uint4 g0 = ((const uint4*)(srcB + (size_t)c0 * F))[lane];
        uint4 g1 = ((const uint4*)(srcB + (size_t)c1 * F))[lane];
        uint4 g2 = ((const uint4*)(srcB + (size_t)c2 * F))[lane];
        uint4 g3 = ((const uint4*)(srcB + (size_t)c3 * F))[lane];
        uint4 g4 = ((const uint4*)(srcB + (size_t)c4 * F))[lane];
        uint4 g5 = ((const uint4*)(srcB + (size_t)c5 * F))[lane];
        uint4 g6 = ((const uint4*)(srcB + (size_t)c6 * F))[lane];
        uint4 g7 = ((const uint4*)(srcB + (size_t)c7 * F))[lane];

        float b0[8], b1[8], b2[8], b3[8], b4[8], b5[8], b6[8], b7[8];
        unpack8h(g0, b0); unpack8h(g1, b1); unpack8h(g2, b2); unpack8h(g3, b3);
        unpack8h(g4, b4); unpack8h(g5, b5); unpack8h(g6, b6); unpack8h(g7, b7);

        #pragma unroll
        for (int i = 0; i < 8; ++i) {
            acc0[i] += v0 * b0[i];
            acc1[i] += v1 * b1[i];
            acc0[i] += v2 * b2[i];
            acc1[i] += v3 * b3[i];
            acc0[i] += v4 * b4[i];
            acc1[i] += v5 * b5[i];
            acc0[i] += v6 * b6[i];
            acc1[i] += v7 * b7[i];
        }
    }

    float y[8];
    #pragma unroll
    for (int i = 0; i < 8; ++i)
        y[i] = alpha * (acc0[i] + acc1[i]) + beta * a[i];

    ((uint4*)(dst + (size_t)n * F))[lane] = pack8h(y);
}

// ---------------- MFMA projection over a chunk (kcnt <= K_S), f16 ----------
// per wave: one node; tile M=32(bt) x N=32(cout), K=kcnt*16.
// A: m=L&31, kk=8*(L>>5)+j ; C/D: col=L&31, row=(reg&3)+8*(reg>>2)+4*(L>>5)

__global__ __launch_bounds__(256) void proj_mfma_kernel(
        const u16* __restrict__ ring, int R, int k0, int kcnt,
        const u16* __restrict__ wtfrag, float* __restrict__ out, int accumulate) {
    const int lane = threadIdx.x & 63;
    const int n = (blockIdx.x << 2) + (threadIdx.x >> 6);
    if (n >= N_NODES) return;
    const int col = lane & 31;
    const int grp = lane >> 5;
    const size_t aoff = (size_t)n * F + (size_t)col * 16 + grp * 8;

    union U { uint4 u; half8 h; };
    float16 acc0 = {};
    float16 acc1 = {};
    int j = 0;
    for (; j + 2 <= kcnt; j += 2) {
        int ka = k0 + j, kb = k0 + j + 1;
        U a0, b0, a1, b1;
        a0.u = *(const uint4*)(ring + (size_t)(ka % R) * RING_ELEMS + aoff);
        b0.u = *(const uint4*)(wtfrag + (size_t)ka * 512 + lane * 8);
        a1.u = *(const uint4*)(ring + (size_t)(kb % R) * RING_ELEMS + aoff);
        b1.u = *(const uint4*)(wtfrag + (size_t)kb * 512 + lane * 8);
        acc0 = __builtin_amdgcn_mfma_f32_32x32x16_f16(a0.h, b0.h, acc0, 0, 0, 0);
        acc1 = __builtin_amdgcn_mfma_f32_32x32x16_f16(a1.h, b1.h, acc1, 0, 0, 0);
    }
    if (j < kcnt) {
        int ka = k0 + j;
        U a0, b0;
        a0.u = *(const uint4*)(ring + (size_t)(ka % R) * RING_ELEMS + aoff);
        b0.u = *(const uint4*)(wtfrag + (size_t)ka * 512 + lane * 8);
        acc0 = __builtin_amdgcn_mfma_f32_32x32x16_f16(a0.h, b0.h, acc0, 0, 0, 0);
    }

    #pragma unroll
    for (int r = 0; r < 16; ++r) {
        int bt = (r & 3) + 8 * (r >> 2) + 4 * grp;
        float* op = out + ((size_t)bt * N_NODES + n) * C_OUT + col;
        float val = acc0[r] + acc1[r];
        if (accumulate) *op += val;
        else            *op  = val;
    }
}

// ---------------- host launch ----------------

extern "C" void kernel_launch(void* const* d_in, const int* in_sizes, int n_in,
                              void* d_out, int out_size, void* d_ws, size_t ws_size,
                              hipStream_t stream) {
    const float* x    = (const float*)d_in[0];
    const int*   erow = (const int*)  d_in[1];
    const int*   ecol = (const int*)  d_in[2];
    const float* eval = (const float*)d_in[3];
    const float* W    = (const float*)d_in[4];
    float* out = (float*)d_out;

    char* ws = (char*)d_ws;
    size_t o = 0;
    auto alloc = [&](size_t bytes) -> char* {
        o = (o + 511) & ~(size_t)511;
        char* r = ws + o;
        o += bytes;
        return r;
    };
    int*   cnt     = (int*)  alloc((size_t)N_NODES * 4);
    int*   row_ptr = (int*)  alloc((size_t)(N_NODES + 1) * 4);
    int*   cursor  = (int*)  alloc((size_t)N_NODES * 4);
    int2*  cpack   = (int2*) alloc((size_t)NNZ_PAD_MAX * 8);
    u16*   wtfrag  = (u16*)  alloc((size_t)K_S * 512 * 2);

    // ring gets everything that's left; R = 20 (~210 MB) -> single proj pass,
    // gracefully degrades to chunked passes on smaller workspaces.
    o = (o + 511) & ~(size_t)511;
    int R = (int)((ws_size - o) / RING_BYTES);
    if (R > K_S) R = K_S;
    if (R < 3)  R = 3;
    u16* ring = (u16*)(ws + o);
    auto slot = [&](int k) -> u16* { return ring + (size_t)(k % R) * RING_ELEMS; };

    // CSR build: 5 parallel kernels
    init_kernel<<<(N_NODES + K_S * 512 + 255) / 256, 256, 0, stream>>>(W, cnt, wtfrag);
    count_kernel<<<(NNZ_E + 255) / 256, 256, 0, stream>>>(erow, cnt);
    scan_kernel<<<1, 256, 0, stream>>>(cnt, row_ptr, cursor);
    scatter_kernel<<<(NNZ_E + 255) / 256, 256, 0, stream>>>(erow, ecol, eval, cursor, cpack);
    finalize_kernel<<<(N_NODES + 255) / 256, 256, 0, stream>>>(row_ptr, cursor, cpack);

    const int grid4 = (N_NODES + 3) / 4;
    int c0 = 0;
    auto maybe_pass = [&](int k_done) {
        int target = K_S - c0;
        if (target > R) target = R;   // chunk == R safe (stream-ordered)
        if (target > 0 && (k_done - c0 + 1) == target) {
            proj_mfma_kernel<<<grid4, 256, 0, stream>>>(
                ring, R, c0, target, wtfrag, out, (c0 > 0) ? 1 : 0);
            c0 += target;
        }
    };

    // k=0,1 fused: T0 (transform) + T1 (gather from fp32 x), one dispatch
    spmm_first_kernel<<<grid4, 256, 0, stream>>>(x, row_ptr, cpack, slot(0), slot(1));
    maybe_pass(0);
    maybe_pass(1);

    // Tk = 2 L T_{k-1} - T_{k-2}
    for (int k = 2; k < K_S; ++k) {
        spmm_step_kernel<<<grid4, 256, 0, stream>>>(
            slot(k - 1), slot(k - 2), slot(k), row_ptr, cpack, 2.f, -1.f);
        maybe_pass(k);
    }
}

// Round 7
// 448.359 us; speedup vs baseline: 1.6554x; 1.0540x over previous
//
#include <hip/hip_runtime.h>

#define N_NODES 10242
#define NNZ_E   71694
// rows padded to multiple of 8, +64 slack for cooperative over-read
#define NNZ_PAD_MAX (NNZ_E + 7 * N_NODES + 64)
#define BT      32      // B*T
#define C_IN    16
#define K_S     20
#define C_OUT   32
#define F       512     // BT * C_IN
typedef unsigned short u16;
typedef unsigned int   u32;

#define RING_ELEMS ((size_t)N_NODES * F)    // f16 elems per ring slot, layout [n][bt*16+c]
#define RING_BYTES (RING_ELEMS * 2)         // ~10.5 MB

#define OVFL_FLAG (1 << 30)

typedef __attribute__((ext_vector_type(8)))  _Float16 half8;
typedef __attribute__((ext_vector_type(16))) float    float16;

__device__ __forceinline__ void unpack8h(uint4 u, float* f) {
    union { uint4 u; _Float16 h[8]; } v; v.u = u;
    #pragma unroll
    for (int i = 0; i < 8; ++i) f[i] = (float)v.h[i];
}
__device__ __forceinline__ uint4 pack8h(const float* f) {
    union { uint4 u; _Float16 h[8]; } v;
    #pragma unroll
    for (int i = 0; i < 8; ++i) v.h[i] = (_Float16)f[i];
    return v.u;
}
__device__ __forceinline__ u16 f2h(float f) {
    union { _Float16 h; u16 u; } v; v.h = (_Float16)f; return v.u;
}

// ---------------- parallel CSR build (5 small wide-grid kernels) -----------
// Determinism: scatter order is nondeterministic, but each row's (col,valbits)
// multiset is fixed; in-row sort by (col, valbits) makes the final CSR — and
// hence the f32 accumulation order — fully deterministic. Rows padded to x8
// with (col=0, val=0) entries (contribute exactly 0). finalize additionally
// emits a FIXED-STRIDE 16-entry table epk16[n] (first 16 sorted entries,
// zero-padded; bit30 of entry 15's col flags >16 real edges -> overflow path).

__global__ __launch_bounds__(256) void init_kernel(
        const float* __restrict__ W, int* __restrict__ cnt,
        u16* __restrict__ wtfrag) {
    int i = blockIdx.x * 256 + threadIdx.x;
    if (i < N_NODES) cnt[i] = 0;
    int w = i - N_NODES;
    if (w >= 0 && w < K_S * 64 * 8) {
        // B-frag for v_mfma_f32_32x32x16_f16: lane L, reg j ->
        // B[k=8*(L>>5)+j][col=L&31] = W[cout=col][c=k][k_cheb]
        int j    = w & 7;
        int lane = (w >> 3) & 63;
        int k    = w >> 9;
        int cout = lane & 31;
        int c    = ((lane >> 5) << 3) + j;
        wtfrag[w] = f2h(W[cout * (C_IN * K_S) + c * K_S + k]);
    }
}

__global__ __launch_bounds__(256) void count_kernel(
        const int* __restrict__ erow, int* cnt) {
    int e = blockIdx.x * 256 + threadIdx.x;
    if (e < NNZ_E) atomicAdd(&cnt[erow[e]], 1);
}

__global__ __launch_bounds__(256) void scan_kernel(
        const int* __restrict__ cnt, int* row_ptr, int* cursor) {
    const int T = 256;
    const int chunk = (N_NODES + T - 1) / T;  // 41
    __shared__ int part[T];
    int t = threadIdx.x;
    int base = t * chunk;
    int s = 0;
    for (int i = 0; i < chunk; ++i) {
        int idx = base + i;
        if (idx < N_NODES) s += (cnt[idx] + 7) & ~7;
    }
    part[t] = s;
    __syncthreads();
    for (int off = 1; off < T; off <<= 1) {
        int v = (t >= off) ? part[t - off] : 0;
        __syncthreads();
        part[t] += v;
        __syncthreads();
    }
    int run = (t == 0) ? 0 : part[t - 1];
    for (int i = 0; i < chunk; ++i) {
        int idx = base + i;
        if (idx < N_NODES) {
            row_ptr[idx] = run;
            cursor[idx]  = run;
            run += (cnt[idx] + 7) & ~7;
        }
    }
    if (t == T - 1) row_ptr[N_NODES] = part[T - 1];
}

__global__ __launch_bounds__(256) void scatter_kernel(
        const int* __restrict__ erow, const int* __restrict__ ecol,
        const float* __restrict__ eval, int* cursor, int2* __restrict__ cpack) {
    int e = blockIdx.x * 256 + threadIdx.x;
    if (e < NNZ_E) {
        int p = atomicAdd(&cursor[erow[e]], 1);
        cpack[p] = make_int2(ecol[e], __float_as_int(eval[e]));
    }
}

// per-row sort + pad + fixed-16 pack
__global__ __launch_bounds__(256) void finalize_kernel(
        const int* __restrict__ row_ptr, const int* __restrict__ cursor,
        int2* cpack, int2* __restrict__ epk16) {
    int r = blockIdx.x * 256 + threadIdx.x;
    if (r >= N_NODES) return;
    int sbeg = row_ptr[r];
    int send = cursor[r];        // sbeg + real count
    int pend = row_ptr[r + 1];   // sbeg + padded count
    for (int i = sbeg + 1; i < send; ++i) {
        int2 key = cpack[i];
        int j = i - 1;
        while (j >= sbeg) {
            int2 q = cpack[j];
            bool gt = (q.x > key.x) || (q.x == key.x && (u32)q.y > (u32)key.y);
            if (!gt) break;
            cpack[j + 1] = q;
            --j;
        }
        cpack[j + 1] = key;
    }
    for (int p = send; p < pend; ++p) cpack[p] = make_int2(0, 0);

    // fixed-stride 16-entry slot (first 16 sorted entries, zero-padded)
    int plen = pend - sbeg;
    int2* d16 = epk16 + (size_t)r * 16;
    #pragma unroll
    for (int p = 0; p < 16; ++p) {
        int2 v = (p < plen) ? cpack[sbeg + p] : make_int2(0, 0);
        if (p == 15 && (send - sbeg) > 16) v.x |= OVFL_FLAG;
        d16[p] = v;
    }
}

// ---------------- transform: x (fp32) -> ring slot 0 (f16) ----------------

__global__ __launch_bounds__(256) void transform_kernel(
        const float* __restrict__ x, u16* __restrict__ T0) {
    int g = blockIdx.x * 256 + threadIdx.x;   // over N*F
    int n   = g >> 9;
    int rem = g & 511;
    int bt  = rem >> 4;
    int c   = rem & 15;
    float v = x[((size_t)bt * N_NODES + n) * C_IN + c];
    T0[(size_t)n * F + rem] = f2h(v);
}

// ---------------- Chebyshev step: wave-per-node, fixed-16 burst ------------
// dst = alpha * L @ srcB + beta * srcA.
// Two memory rounds only: {epk16 row (address = n*16, no row_ptr dep), srcA}
// issued together, then ONE unrolled burst of 16 gathers. Pad entries are
// (col=0, val=0): their gathers hit node 0's row (always cache-hot) and
// contribute exactly 0. Rows with >16 real edges (rare) take the flagged
// overflow path through the original CSR.

__global__ __launch_bounds__(256) void spmm16_kernel(
        const u16* __restrict__ srcB, const u16* __restrict__ srcA,
        u16* __restrict__ dst,
        const int2* __restrict__ epk16,
        const int* __restrict__ row_ptr, const int2* __restrict__ cpack,
        float alpha, float beta) {
    const int lane = threadIdx.x & 63;
    const int n = (blockIdx.x << 2) + (threadIdx.x >> 6);
    if (n >= N_NODES) return;

    // round 1: edge slot (known address) + srcA, independent
    int2 my = epk16[(size_t)n * 16 + (lane & 15)];
    float a[8] = {0,0,0,0,0,0,0,0};
    if (beta != 0.f) {
        uint4 ua = ((const uint4*)(srcA + (size_t)n * F))[lane];
        unpack8h(ua, a);
    }

    // broadcast all 16 (col, val); cols masked to strip the overflow flag
    int   c[16]; float v[16];
    #pragma unroll
    for (int r = 0; r < 16; ++r) {
        c[r] = __builtin_amdgcn_readlane(my.x, r) & 0xFFFF;
        v[r] = __int_as_float(__builtin_amdgcn_readlane(my.y, r));
    }

    // round 2: one burst of 16 gathers (16 KB in flight per wave)
    uint4 g[16];
    #pragma unroll
    for (int r = 0; r < 16; ++r)
        g[r] = ((const uint4*)(srcB + (size_t)c[r] * F))[lane];

    float acc0[8] = {0,0,0,0,0,0,0,0};
    float acc1[8] = {0,0,0,0,0,0,0,0};
    #pragma unroll
    for (int r = 0; r < 16; r += 2) {
        float b0[8], b1[8];
        unpack8h(g[r], b0);
        unpack8h(g[r + 1], b1);
        #pragma unroll
        for (int i = 0; i < 8; ++i) {
            acc0[i] += v[r]     * b0[i];
            acc1[i] += v[r + 1] * b1[i];
        }
    }

    // rare overflow: >16 real edges — walk the original CSR from entry 16
    if (__builtin_amdgcn_readlane(my.x, 15) & OVFL_FLAG) {
        int s = row_ptr[n], e_end = row_ptr[n + 1];
        for (int e = s + 16; e < e_end; e += 8) {
            int2 m2 = cpack[e + (lane & 7)];
            #pragma unroll
            for (int r = 0; r < 8; ++r) {
                int   cc = __builtin_amdgcn_readlane(m2.x, r);
                float vv = __int_as_float(__builtin_amdgcn_readlane(m2.y, r));
                uint4 gg = ((const uint4*)(srcB + (size_t)cc * F))[lane];
                float bb[8];
                unpack8h(gg, bb);
                #pragma unroll
                for (int i = 0; i < 8; ++i) acc0[i] += vv * bb[i];
            }
        }
    }

    float y[8];
    #pragma unroll
    for (int i = 0; i < 8; ++i)
        y[i] = alpha * (acc0[i] + acc1[i]) + beta * a[i];

    ((uint4*)(dst + (size_t)n * F))[lane] = pack8h(y);
}

// ---------------- MFMA projection over a chunk (kcnt <= K_S), f16 ----------
// per wave: one node; tile M=32(bt) x N=32(cout), K=kcnt*16.
// A: m=L&31, kk=8*(L>>5)+j ; C/D: col=L&31, row=(reg&3)+8*(reg>>2)+4*(L>>5)

__global__ __launch_bounds__(256) void proj_mfma_kernel(
        const u16* __restrict__ ring, int R, int k0, int kcnt,
        const u16* __restrict__ wtfrag, float* __restrict__ out, int accumulate) {
    const int lane = threadIdx.x & 63;
    const int n = (blockIdx.x << 2) + (threadIdx.x >> 6);
    if (n >= N_NODES) return;
    const int col = lane & 31;
    const int grp = lane >> 5;
    const size_t aoff = (size_t)n * F + (size_t)col * 16 + grp * 8;

    union U { uint4 u; half8 h; };
    float16 acc0 = {};
    float16 acc1 = {};
    int j = 0;
    for (; j + 2 <= kcnt; j += 2) {
        int ka = k0 + j, kb = k0 + j + 1;
        U a0, b0, a1, b1;
        a0.u = *(const uint4*)(ring + (size_t)(ka % R) * RING_ELEMS + aoff);
        b0.u = *(const uint4*)(wtfrag + (size_t)ka * 512 + lane * 8);
        a1.u = *(const uint4*)(ring + (size_t)(kb % R) * RING_ELEMS + aoff);
        b1.u = *(const uint4*)(wtfrag + (size_t)kb * 512 + lane * 8);
        acc0 = __builtin_amdgcn_mfma_f32_32x32x16_f16(a0.h, b0.h, acc0, 0, 0, 0);
        acc1 = __builtin_amdgcn_mfma_f32_32x32x16_f16(a1.h, b1.h, acc1, 0, 0, 0);
    }
    if (j < kcnt) {
        int ka = k0 + j;
        U a0, b0;
        a0.u = *(const uint4*)(ring + (size_t)(ka % R) * RING_ELEMS + aoff);
        b0.u = *(const uint4*)(wtfrag + (size_t)ka * 512 + lane * 8);
        acc0 = __builtin_amdgcn_mfma_f32_32x32x16_f16(a0.h, b0.h, acc0, 0, 0, 0);
    }

    #pragma unroll
    for (int r = 0; r < 16; ++r) {
        int bt = (r & 3) + 8 * (r >> 2) + 4 * grp;
        float* op = out + ((size_t)bt * N_NODES + n) * C_OUT + col;
        float val = acc0[r] + acc1[r];
        if (accumulate) *op += val;
        else            *op  = val;
    }
}

// ---------------- host launch ----------------

extern "C" void kernel_launch(void* const* d_in, const int* in_sizes, int n_in,
                              void* d_out, int out_size, void* d_ws, size_t ws_size,
                              hipStream_t stream) {
    const float* x    = (const float*)d_in[0];
    const int*   erow = (const int*)  d_in[1];
    const int*   ecol = (const int*)  d_in[2];
    const float* eval = (const float*)d_in[3];
    const float* W    = (const float*)d_in[4];
    float* out = (float*)d_out;

    char* ws = (char*)d_ws;
    size_t o = 0;
    auto alloc = [&](size_t bytes) -> char* {
        o = (o + 511) & ~(size_t)511;
        char* r = ws + o;
        o += bytes;
        return r;
    };
    int*   cnt     = (int*)  alloc((size_t)N_NODES * 4);
    int*   row_ptr = (int*)  alloc((size_t)(N_NODES + 1) * 4);
    int*   cursor  = (int*)  alloc((size_t)N_NODES * 4);
    int2*  cpack   = (int2*) alloc((size_t)NNZ_PAD_MAX * 8);
    int2*  epk16   = (int2*) alloc((size_t)N_NODES * 16 * 8);
    u16*   wtfrag  = (u16*)  alloc((size_t)K_S * 512 * 2);

    // ring gets everything that's left; R = 20 -> single proj pass,
    // gracefully degrades to chunked passes on smaller workspaces.
    o = (o + 511) & ~(size_t)511;
    int R = (int)((ws_size - o) / RING_BYTES);
    if (R > K_S) R = K_S;
    if (R < 3)  R = 3;
    u16* ring = (u16*)(ws + o);
    auto slot = [&](int k) -> u16* { return ring + (size_t)(k % R) * RING_ELEMS; };

    // CSR build: 5 parallel kernels (fixed-16 pack folded into finalize)
    init_kernel<<<(N_NODES + K_S * 512 + 255) / 256, 256, 0, stream>>>(W, cnt, wtfrag);
    count_kernel<<<(NNZ_E + 255) / 256, 256, 0, stream>>>(erow, cnt);
    scan_kernel<<<1, 256, 0, stream>>>(cnt, row_ptr, cursor);
    scatter_kernel<<<(NNZ_E + 255) / 256, 256, 0, stream>>>(erow, ecol, eval, cursor, cpack);
    finalize_kernel<<<(N_NODES + 255) / 256, 256, 0, stream>>>(row_ptr, cursor, cpack, epk16);

    const int grid4 = (N_NODES + 3) / 4;
    int c0 = 0;
    auto maybe_pass = [&](int k_done) {
        int target = K_S - c0;
        if (target > R) target = R;   // chunk == R safe (stream-ordered)
        if (target > 0 && (k_done - c0 + 1) == target) {
            proj_mfma_kernel<<<grid4, 256, 0, stream>>>(
                ring, R, c0, target, wtfrag, out, (c0 > 0) ? 1 : 0);
            c0 += target;
        }
    };

    // T0 -> slot 0
    transform_kernel<<<(int)(RING_ELEMS / 256), 256, 0, stream>>>(x, slot(0));
    maybe_pass(0);

    // T1 = L T0 ; Tk = 2 L T_{k-1} - T_{k-2}
    for (int k = 1; k < K_S; ++k) {
        const u16* srcB = slot(k - 1);
        const u16* srcA = (k >= 2) ? slot(k - 2) : slot(k - 1);  // unread when beta==0
        float alpha = (k == 1) ? 1.f : 2.f;
        float beta  = (k == 1) ? 0.f : -1.f;
        spmm16_kernel<<<grid4, 256, 0, stream>>>(
            srcB, srcA, slot(k), epk16, row_ptr, cpack, alpha, beta);
        maybe_pass(k);
    }
}

// Round 8
// 419.968 us; speedup vs baseline: 1.7674x; 1.0676x over previous
//
#include <hip/hip_runtime.h>

#define N_NODES 10242
#define NNZ_E   71694
// rows padded to multiple of 8, +64 slack for cooperative over-read
#define NNZ_PAD_MAX (NNZ_E + 7 * N_NODES + 64)
#define BT      32      // B*T
#define C_IN    16
#define K_S     20
#define C_OUT   32
#define F       512     // BT * C_IN
typedef unsigned short u16;
typedef unsigned int   u32;
typedef unsigned long long u64;

#define RING_ELEMS ((size_t)N_NODES * F)    // f16 elems per ring slot, layout [n][bt*16+c]
#define RING_BYTES (RING_ELEMS * 2)         // ~10.5 MB

#define OVFL_FLAG (1 << 30)

typedef __attribute__((ext_vector_type(8)))  _Float16 half8;
typedef __attribute__((ext_vector_type(16))) float    float16;

__device__ __forceinline__ void unpack8h(uint4 u, float* f) {
    union { uint4 u; _Float16 h[8]; } v; v.u = u;
    #pragma unroll
    for (int i = 0; i < 8; ++i) f[i] = (float)v.h[i];
}
__device__ __forceinline__ uint4 pack8h(const float* f) {
    union { uint4 u; _Float16 h[8]; } v;
    #pragma unroll
    for (int i = 0; i < 8; ++i) v.h[i] = (_Float16)f[i];
    return v.u;
}
__device__ __forceinline__ u16 f2h(float f) {
    union { _Float16 h; u16 u; } v; v.h = (_Float16)f; return v.u;
}

// ---------------- parallel CSR build (5 small wide-grid kernels) -----------
// Determinism: scatter order is nondeterministic, but each row's (col,valbits)
// multiset is fixed; rank-sort by (col, valbits, pos) produces ascending
// (col,valbits) order — duplicates are bit-identical, so the sorted content
// (and hence f32 accumulation order) is fully deterministic. Rows padded to
// x8 with (col=0, val=0) entries (contribute exactly 0). finalize emits a
// FIXED-STRIDE 16-entry table epk16[n] (first 16 sorted entries, zero-padded;
// bit30 of entry 15's col flags >16 real edges -> overflow path).

__global__ __launch_bounds__(256) void init_kernel(
        const float* __restrict__ W, int* __restrict__ cnt,
        u16* __restrict__ wtfrag) {
    int i = blockIdx.x * 256 + threadIdx.x;
    if (i < N_NODES) cnt[i] = 0;
    int w = i - N_NODES;
    if (w >= 0 && w < K_S * 64 * 8) {
        // B-frag for v_mfma_f32_32x32x16_f16: lane L, reg j ->
        // B[k=8*(L>>5)+j][col=L&31] = W[cout=col][c=k][k_cheb]
        int j    = w & 7;
        int lane = (w >> 3) & 63;
        int k    = w >> 9;
        int cout = lane & 31;
        int c    = ((lane >> 5) << 3) + j;
        wtfrag[w] = f2h(W[cout * (C_IN * K_S) + c * K_S + k]);
    }
}

__global__ __launch_bounds__(256) void count_kernel(
        const int* __restrict__ erow, int* cnt) {
    int e = blockIdx.x * 256 + threadIdx.x;
    if (e < NNZ_E) atomicAdd(&cnt[erow[e]], 1);
}

__global__ __launch_bounds__(256) void scan_kernel(
        const int* __restrict__ cnt, int* row_ptr, int* cursor) {
    const int T = 256;
    const int chunk = (N_NODES + T - 1) / T;  // 41
    __shared__ int part[T];
    int t = threadIdx.x;
    int base = t * chunk;
    int s = 0;
    for (int i = 0; i < chunk; ++i) {
        int idx = base + i;
        if (idx < N_NODES) s += (cnt[idx] + 7) & ~7;
    }
    part[t] = s;
    __syncthreads();
    for (int off = 1; off < T; off <<= 1) {
        int v = (t >= off) ? part[t - off] : 0;
        __syncthreads();
        part[t] += v;
        __syncthreads();
    }
    int run = (t == 0) ? 0 : part[t - 1];
    for (int i = 0; i < chunk; ++i) {
        int idx = base + i;
        if (idx < N_NODES) {
            row_ptr[idx] = run;
            cursor[idx]  = run;
            run += (cnt[idx] + 7) & ~7;
        }
    }
    if (t == T - 1) row_ptr[N_NODES] = part[T - 1];
}

__global__ __launch_bounds__(256) void scatter_kernel(
        const int* __restrict__ erow, const int* __restrict__ ecol,
        const float* __restrict__ eval, int* cursor, int2* __restrict__ cpack) {
    int e = blockIdx.x * 256 + threadIdx.x;
    if (e < NNZ_E) {
        int p = atomicAdd(&cursor[erow[e]], 1);
        cpack[p] = make_int2(ecol[e], __float_as_int(eval[e]));
    }
}

// wave-per-row RANK SORT + pad + fixed-16 pack. All lanes run the uniform
// shfl broadcast loop; rank = #{keys < mine} with (col,valbits,pos) tie-break
// (strict total order -> ranks are a bijection over the 64 lanes). No serial
// dependent-load chains, no re-reads.
__global__ __launch_bounds__(256) void finalize_kernel(
        const int* __restrict__ row_ptr, const int* __restrict__ cursor,
        int2* cpack, int2* __restrict__ epk16) {
    const int lane = threadIdx.x & 63;
    const int r = (blockIdx.x << 2) + (threadIdx.x >> 6);
    if (r >= N_NODES) return;
    const int sbeg = row_ptr[r];
    const int send = cursor[r];      // sbeg + real count
    const int pend = row_ptr[r + 1]; // sbeg + padded count
    const int rlen = send - sbeg;
    const int plen = pend - sbeg;

    if (plen > 64) {                 // essentially impossible; serial fallback
        if (lane == 0) {
            for (int i = sbeg + 1; i < send; ++i) {
                int2 key = cpack[i];
                int j = i - 1;
                while (j >= sbeg) {
                    int2 q = cpack[j];
                    bool gt = (q.x > key.x) || (q.x == key.x && (u32)q.y > (u32)key.y);
                    if (!gt) break;
                    cpack[j + 1] = q; --j;
                }
                cpack[j + 1] = key;
            }
            for (int p = send; p < pend; ++p) cpack[p] = make_int2(0, 0);
            for (int p = 0; p < 16; ++p) {
                int2 v = (p < plen) ? cpack[sbeg + p] : make_int2(0, 0);
                if (p == 15 && rlen > 16) v.x |= OVFL_FLAG;
                epk16[(size_t)r * 16 + p] = v;
            }
        }
        return;
    }

    const bool real = (lane < rlen);
    int2 e = real ? cpack[sbeg + lane] : make_int2(0, 0);
    const u64 ki = ((u64)(u32)e.x << 32) | (u32)e.y;

    int rank = 0;
    for (int j = 0; j < rlen; ++j) {      // wave-uniform bound
        int cx = __shfl(e.x, j, 64);
        int cy = __shfl(e.y, j, 64);
        u64 kj = ((u64)(u32)cx << 32) | (u32)cy;
        if (kj < ki || (kj == ki && j < lane)) ++rank;
    }
    if (!real) rank = lane;               // pads/idle keep own position

    // sorted cpack: reals at [0,rlen), zero pads at [rlen,plen)
    if (lane < plen) cpack[sbeg + rank] = real ? e : make_int2(0, 0);

    // epk16 direct from ranks (positions 0..15 covered bijectively)
    int2 v16 = real ? e : make_int2(0, 0);
    if (rank == 15 && rlen > 16) v16.x |= OVFL_FLAG;
    if (rank < 16) epk16[(size_t)r * 16 + rank] = v16;
}

// ---------------- transform: x (fp32) -> ring slot 0 (f16) ----------------

__global__ __launch_bounds__(256) void transform_kernel(
        const float* __restrict__ x, u16* __restrict__ T0) {
    int g = blockIdx.x * 256 + threadIdx.x;   // over N*F
    int n   = g >> 9;
    int rem = g & 511;
    int bt  = rem >> 4;
    int c   = rem & 15;
    float v = x[((size_t)bt * N_NODES + n) * C_IN + c];
    T0[(size_t)n * F + rem] = f2h(v);
}

// ---------------- Chebyshev step: wave-per-node, fixed-16 burst ------------
// dst = alpha * L @ srcB + beta * srcA.
// Two memory rounds only: {epk16 row (address = n*16, no row_ptr dep), srcA}
// issued together, then ONE unrolled burst of 16 gathers. Pad entries are
// (col=0, val=0): their gathers hit node 0's row (always cache-hot) and
// contribute exactly 0. Rows with >16 real edges (rare) take the flagged
// overflow path through the original CSR.

__global__ __launch_bounds__(256) void spmm16_kernel(
        const u16* __restrict__ srcB, const u16* __restrict__ srcA,
        u16* __restrict__ dst,
        const int2* __restrict__ epk16,
        const int* __restrict__ row_ptr, const int2* __restrict__ cpack,
        float alpha, float beta) {
    const int lane = threadIdx.x & 63;
    const int n = (blockIdx.x << 2) + (threadIdx.x >> 6);
    if (n >= N_NODES) return;

    // round 1: edge slot (known address) + srcA, independent
    int2 my = epk16[(size_t)n * 16 + (lane & 15)];
    float a[8] = {0,0,0,0,0,0,0,0};
    if (beta != 0.f) {
        uint4 ua = ((const uint4*)(srcA + (size_t)n * F))[lane];
        unpack8h(ua, a);
    }

    // broadcast all 16 (col, val); cols masked to strip the overflow flag
    int   c[16]; float v[16];
    #pragma unroll
    for (int r = 0; r < 16; ++r) {
        c[r] = __builtin_amdgcn_readlane(my.x, r) & 0xFFFF;
        v[r] = __int_as_float(__builtin_amdgcn_readlane(my.y, r));
    }

    // round 2: one burst of 16 gathers (16 KB in flight per wave)
    uint4 g[16];
    #pragma unroll
    for (int r = 0; r < 16; ++r)
        g[r] = ((const uint4*)(srcB + (size_t)c[r] * F))[lane];

    float acc0[8] = {0,0,0,0,0,0,0,0};
    float acc1[8] = {0,0,0,0,0,0,0,0};
    #pragma unroll
    for (int r = 0; r < 16; r += 2) {
        float b0[8], b1[8];
        unpack8h(g[r], b0);
        unpack8h(g[r + 1], b1);
        #pragma unroll
        for (int i = 0; i < 8; ++i) {
            acc0[i] += v[r]     * b0[i];
            acc1[i] += v[r + 1] * b1[i];
        }
    }

    // rare overflow: >16 real edges — walk the original CSR from entry 16
    if (__builtin_amdgcn_readlane(my.x, 15) & OVFL_FLAG) {
        int s = row_ptr[n], e_end = row_ptr[n + 1];
        for (int e = s + 16; e < e_end; e += 8) {
            int2 m2 = cpack[e + (lane & 7)];
            #pragma unroll
            for (int r = 0; r < 8; ++r) {
                int   cc = __builtin_amdgcn_readlane(m2.x, r);
                float vv = __int_as_float(__builtin_amdgcn_readlane(m2.y, r));
                uint4 gg = ((const uint4*)(srcB + (size_t)cc * F))[lane];
                float bb[8];
                unpack8h(gg, bb);
                #pragma unroll
                for (int i = 0; i < 8; ++i) acc0[i] += vv * bb[i];
            }
        }
    }

    float y[8];
    #pragma unroll
    for (int i = 0; i < 8; ++i)
        y[i] = alpha * (acc0[i] + acc1[i]) + beta * a[i];

    ((uint4*)(dst + (size_t)n * F))[lane] = pack8h(y);
}

// ---------------- MFMA projection over a chunk (kcnt <= K_S), f16 ----------
// per wave: one node; tile M=32(bt) x N=32(cout), K=kcnt*16.
// A: m=L&31, kk=8*(L>>5)+j ; C/D: col=L&31, row=(reg&3)+8*(reg>>2)+4*(L>>5)

__global__ __launch_bounds__(256) void proj_mfma_kernel(
        const u16* __restrict__ ring, int R, int k0, int kcnt,
        const u16* __restrict__ wtfrag, float* __restrict__ out, int accumulate) {
    const int lane = threadIdx.x & 63;
    const int n = (blockIdx.x << 2) + (threadIdx.x >> 6);
    if (n >= N_NODES) return;
    const int col = lane & 31;
    const int grp = lane >> 5;
    const size_t aoff = (size_t)n * F + (size_t)col * 16 + grp * 8;

    union U { uint4 u; half8 h; };
    float16 acc0 = {};
    float16 acc1 = {};
    int j = 0;
    for (; j + 2 <= kcnt; j += 2) {
        int ka = k0 + j, kb = k0 + j + 1;
        U a0, b0, a1, b1;
        a0.u = *(const uint4*)(ring + (size_t)(ka % R) * RING_ELEMS + aoff);
        b0.u = *(const uint4*)(wtfrag + (size_t)ka * 512 + lane * 8);
        a1.u = *(const uint4*)(ring + (size_t)(kb % R) * RING_ELEMS + aoff);
        b1.u = *(const uint4*)(wtfrag + (size_t)kb * 512 + lane * 8);
        acc0 = __builtin_amdgcn_mfma_f32_32x32x16_f16(a0.h, b0.h, acc0, 0, 0, 0);
        acc1 = __builtin_amdgcn_mfma_f32_32x32x16_f16(a1.h, b1.h, acc1, 0, 0, 0);
    }
    if (j < kcnt) {
        int ka = k0 + j;
        U a0, b0;
        a0.u = *(const uint4*)(ring + (size_t)(ka % R) * RING_ELEMS + aoff);
        b0.u = *(const uint4*)(wtfrag + (size_t)ka * 512 + lane * 8);
        acc0 = __builtin_amdgcn_mfma_f32_32x32x16_f16(a0.h, b0.h, acc0, 0, 0, 0);
    }

    #pragma unroll
    for (int r = 0; r < 16; ++r) {
        int bt = (r & 3) + 8 * (r >> 2) + 4 * grp;
        float* op = out + ((size_t)bt * N_NODES + n) * C_OUT + col;
        float val = acc0[r] + acc1[r];
        if (accumulate) *op += val;
        else            *op  = val;
    }
}

// ---------------- host launch ----------------

extern "C" void kernel_launch(void* const* d_in, const int* in_sizes, int n_in,
                              void* d_out, int out_size, void* d_ws, size_t ws_size,
                              hipStream_t stream) {
    const float* x    = (const float*)d_in[0];
    const int*   erow = (const int*)  d_in[1];
    const int*   ecol = (const int*)  d_in[2];
    const float* eval = (const float*)d_in[3];
    const float* W    = (const float*)d_in[4];
    float* out = (float*)d_out;

    char* ws = (char*)d_ws;
    size_t o = 0;
    auto alloc = [&](size_t bytes) -> char* {
        o = (o + 511) & ~(size_t)511;
        char* r = ws + o;
        o += bytes;
        return r;
    };
    int*   cnt     = (int*)  alloc((size_t)N_NODES * 4);
    int*   row_ptr = (int*)  alloc((size_t)(N_NODES + 1) * 4);
    int*   cursor  = (int*)  alloc((size_t)N_NODES * 4);
    int2*  cpack   = (int2*) alloc((size_t)NNZ_PAD_MAX * 8);
    int2*  epk16   = (int2*) alloc((size_t)N_NODES * 16 * 8);
    u16*   wtfrag  = (u16*)  alloc((size_t)K_S * 512 * 2);

    // ring gets everything that's left; R = 20 -> single proj pass,
    // gracefully degrades to chunked passes on smaller workspaces.
    o = (o + 511) & ~(size_t)511;
    int R = (int)((ws_size - o) / RING_BYTES);
    if (R > K_S) R = K_S;
    if (R < 3)  R = 3;
    u16* ring = (u16*)(ws + o);
    auto slot = [&](int k) -> u16* { return ring + (size_t)(k % R) * RING_ELEMS; };

    // CSR build: 5 parallel kernels (fixed-16 pack folded into finalize)
    init_kernel<<<(N_NODES + K_S * 512 + 255) / 256, 256, 0, stream>>>(W, cnt, wtfrag);
    count_kernel<<<(NNZ_E + 255) / 256, 256, 0, stream>>>(erow, cnt);
    scan_kernel<<<1, 256, 0, stream>>>(cnt, row_ptr, cursor);
    scatter_kernel<<<(NNZ_E + 255) / 256, 256, 0, stream>>>(erow, ecol, eval, cursor, cpack);
    finalize_kernel<<<(N_NODES + 3) / 4, 256, 0, stream>>>(row_ptr, cursor, cpack, epk16);

    const int grid4 = (N_NODES + 3) / 4;
    int c0 = 0;
    auto maybe_pass = [&](int k_done) {
        int target = K_S - c0;
        if (target > R) target = R;   // chunk == R safe (stream-ordered)
        if (target > 0 && (k_done - c0 + 1) == target) {
            proj_mfma_kernel<<<grid4, 256, 0, stream>>>(
                ring, R, c0, target, wtfrag, out, (c0 > 0) ? 1 : 0);
            c0 += target;
        }
    };

    // T0 -> slot 0
    transform_kernel<<<(int)(RING_ELEMS / 256), 256, 0, stream>>>(x, slot(0));
    maybe_pass(0);

    // T1 = L T0 ; Tk = 2 L T_{k-1} - T_{k-2}
    for (int k = 1; k < K_S; ++k) {
        const u16* srcB = slot(k - 1);
        const u16* srcA = (k >= 2) ? slot(k - 2) : slot(k - 1);  // unread when beta==0
        float alpha = (k == 1) ? 1.f : 2.f;
        float beta  = (k == 1) ? 0.f : -1.f;
        spmm16_kernel<<<grid4, 256, 0, stream>>>(
            srcB, srcA, slot(k), epk16, row_ptr, cpack, alpha, beta);
        maybe_pass(k);
    }
}